// Round 10
// baseline (402.614 us; speedup 1.0000x reference)
//
#include <hip/hip_runtime.h>
#include <hip/hip_cooperative_groups.h>

namespace cg = cooperative_groups;

typedef __attribute__((ext_vector_type(8))) short short8;
typedef __attribute__((ext_vector_type(4))) short short4v;
typedef __attribute__((ext_vector_type(4))) float float4v;
typedef __attribute__((ext_vector_type(4))) unsigned uint4v;
typedef __attribute__((ext_vector_type(2))) unsigned uint2v;
typedef __attribute__((ext_vector_type(4))) _Float16 half4;

constexpr int T  = 2048;
constexpr int DM = 256;
constexpr int DK = 32;

__device__ inline short f2bf(float f) {
  unsigned u = __builtin_bit_cast(unsigned, f);
  u += 0x7fff + ((u >> 16) & 1);            // RNE
  return (short)(u >> 16);
}

__device__ inline unsigned pk2(float a, float b) {
#if __has_builtin(__builtin_amdgcn_cvt_pk_bf16_f32)
  auto r = __builtin_amdgcn_cvt_pk_bf16_f32(a, b);
  return __builtin_bit_cast(unsigned, r);
#else
  unsigned ua = __builtin_bit_cast(unsigned, a);
  ua = (ua + 0x7fff + ((ua >> 16) & 1)) >> 16;
  unsigned ub = __builtin_bit_cast(unsigned, b);
  ub = (ub + 0x7fff + ((ub >> 16) & 1)) >> 16;
  return ua | (ub << 16);
#endif
}

__device__ inline float fexp2(float x) {
#if __has_builtin(__builtin_amdgcn_exp2f)
  return __builtin_amdgcn_exp2f(x);
#else
  return exp2f(x);
#endif
}

__device__ inline short8 load8_bf(const float* __restrict__ p) {
  float4v a = *(const float4v*)p;
  float4v b = *(const float4v*)(p + 4);
  uint4v u;
  u[0] = pk2(a[0], a[1]); u[1] = pk2(a[2], a[3]);
  u[2] = pk2(b[0], b[1]); u[3] = pk2(b[2], b[3]);
  return __builtin_bit_cast(short8, u);
}

// ======================= phase bodies (shared by mega + fallback) ==========
// LDS layout: As at smem+0 (128x40 shorts), Bs at smem+10240 (up to 128x40).
// attn uses the whole 71680 B (Pt 2x128x136 + psum 128x4 floats).

// K/Q projection: 128x64 tile, fp32 in -> bf16 out, K=N=256.
__device__ inline void proj_body(const float* __restrict__ A,
                                 const float* __restrict__ Bw,
                                 const float* __restrict__ bias,
                                 short* __restrict__ C, float oscale,
                                 int bx, int by, char* smem) {
  auto As = (short(*)[40])smem;
  auto Bs = (short(*)[40])(smem + 10240);
  const int tid  = threadIdx.x;
  const int wave = tid >> 6, lane = tid & 63;
  const int l15  = lane & 15, quad = lane >> 4;
  const int wm   = (wave & 1) * 64, wn = (wave >> 1) * 32;
  const long Abase = (long)bx * 128;
  const long Bbase = (long)by * 64;

  float4v acc[4][2];
  for (int i = 0; i < 4; i++)
    for (int j = 0; j < 2; j++)
      for (int r = 0; r < 4; r++) acc[i][j][r] = 0.f;

  const int srow = tid >> 2;
  const int sc8  = (tid & 3) * 8;

  for (int k0 = 0; k0 < 256; k0 += 32) {
    __syncthreads();
    for (int i = 0; i < 2; i++) {
      int row = srow + i * 64;
      *(short8*)&As[row][sc8] = load8_bf(A + (Abase + row) * 256 + k0 + sc8);
    }
    *(short8*)&Bs[srow][sc8] = load8_bf(Bw + (Bbase + srow) * 256 + k0 + sc8);
    __syncthreads();
    short8 af[4], bfr[2];
    for (int ms = 0; ms < 4; ms++) af[ms]  = *(const short8*)&As[wm + ms*16 + l15][quad*8];
    for (int ns = 0; ns < 2; ns++) bfr[ns] = *(const short8*)&Bs[wn + ns*16 + l15][quad*8];
    for (int ms = 0; ms < 4; ms++)
      for (int ns = 0; ns < 2; ns++)
        acc[ms][ns] = __builtin_amdgcn_mfma_f32_16x16x32_bf16(af[ms], bfr[ns], acc[ms][ns], 0, 0, 0);
  }

  for (int ms = 0; ms < 4; ms++) {
    int rowl = wm + ms*16 + quad*4;
    for (int ns = 0; ns < 2; ns++) {
      int col = (int)Bbase + wn + ns*16 + l15;
      float bv = bias[col];
      for (int r = 0; r < 4; r++) {
        long row = Abase + rowl + r;
        C[row * 256 + col] = f2bf((acc[ms][ns][r] + bv) * oscale);
      }
    }
  }
}

// Wfused[h][n][k] = sum_d WO_w[n, d*8+h] * WV_w[h*256+d, k], bf16 out.
__device__ inline void wf_body(const float* __restrict__ WO_w,
                               const float* __restrict__ WV_w,
                               short* __restrict__ Wf,
                               int h, int bx, int by, char* smem) {
  auto As = (short(*)[40])smem;
  auto Bs = (short(*)[40])(smem + 10240);
  const int tid  = threadIdx.x;
  const int wave = tid >> 6, lane = tid & 63;
  const int l15  = lane & 15, quad = lane >> 4;
  const int wm   = (wave & 1) * 64, wn = (wave >> 1) * 32;
  const int srow = tid >> 2, sc8 = (tid & 3) * 8;

  float4v acc[4][2];
  for (int i = 0; i < 4; i++)
    for (int j = 0; j < 2; j++)
      for (int r = 0; r < 4; r++) acc[i][j][r] = 0.f;

  for (int d0 = 0; d0 < 256; d0 += 32) {
    __syncthreads();
    for (int i = 0; i < 2; i++) {
      int row = srow + i * 64;
      for (int j = 0; j < 8; j++)
        As[row][sc8 + j] = f2bf(WO_w[(bx*128 + row) * 2048 + (d0 + sc8 + j) * 8 + h]);
    }
    for (int j = 0; j < 8; j++)
      Bs[srow][sc8 + j] = f2bf(WV_w[((h*256) + d0 + sc8 + j) * 256 + by*64 + srow]);
    __syncthreads();
    short8 af[4], bfr[2];
    for (int ms = 0; ms < 4; ms++) af[ms]  = *(const short8*)&As[wm + ms*16 + l15][quad*8];
    for (int ns = 0; ns < 2; ns++) bfr[ns] = *(const short8*)&Bs[wn + ns*16 + l15][quad*8];
    for (int ms = 0; ms < 4; ms++)
      for (int ns = 0; ns < 2; ns++)
        acc[ms][ns] = __builtin_amdgcn_mfma_f32_16x16x32_bf16(af[ms], bfr[ns], acc[ms][ns], 0, 0, 0);
  }
  for (int ms = 0; ms < 4; ms++) {
    int m = bx*128 + wm + ms*16 + quad*4;
    for (int ns = 0; ns < 2; ns++) {
      int col = by*64 + wn + ns*16 + l15;
      for (int r = 0; r < 4; r++)
        Wf[((long)h*256 + m + r) * 256 + col] = f2bf(acc[ms][ns][r]);
    }
  }
}

// cbias[h][n] = sum_d WV_b[h*256+d] * WO_w[n, d*8+h]
__device__ inline void cbias_body(const float* __restrict__ WV_b,
                                  const float* __restrict__ WO_w,
                                  float* __restrict__ cbias,
                                  int idx, char* smem) {
  float* cb_s = (float*)smem;           // [16][17]
  const int tid = threadIdx.x;
  const int h = idx >> 4, ng = idx & 15;
  const int ni = tid & 15, di = tid >> 4;
  const int n = ng * 16 + ni;
  float acc = 0.f;
  for (int j = 0; j < 16; j++) {
    int d = di * 16 + j;
    acc += WV_b[h*256 + d] * WO_w[n * 2048 + d*8 + h];
  }
  cb_s[ni*17 + di] = acc;
  __syncthreads();
  if (tid < 16) {
    float s = 0.f;
    for (int d2 = 0; d2 < 16; d2++) s += cb_s[tid*17 + d2];
    cbias[h*256 + ng*16 + tid] = s;
  }
  __syncthreads();
}

// Ut[b][h*256+n][s] = sum_k Wf[h*256+n][k]*value_x[b*2048+s][k] + cbias
// 128x128 tile; bx in [0,16) over M=2048, by in [0,64) over N=8192.
__device__ inline void ut_body(const short* __restrict__ Wf,
                               const float* __restrict__ Bw,
                               const float* __restrict__ cbias,
                               short* __restrict__ Ut,
                               int bx, int by, char* smem) {
  auto As = (short(*)[40])smem;
  auto Bs = (short(*)[40])(smem + 10240);
  const int tid  = threadIdx.x;
  const int wave = tid >> 6, lane = tid & 63;
  const int l15  = lane & 15, quad = lane >> 4;
  const int wm   = (wave & 1) * 64, wn = (wave >> 1) * 64;
  const long Abase = (long)bx * 128;
  const long Bbase = (long)by * 128;

  float4v acc[4][4];
  for (int i = 0; i < 4; i++)
    for (int j = 0; j < 4; j++)
      for (int r = 0; r < 4; r++) acc[i][j][r] = 0.f;

  const int srow = tid >> 2;
  const int sc8  = (tid & 3) * 8;

  for (int k0 = 0; k0 < 256; k0 += 32) {
    __syncthreads();
    for (int i = 0; i < 2; i++) {
      int row = srow + i * 64;
      *(short8*)&As[row][sc8] = *(const short8*)(Wf + (Abase + row) * 256 + k0 + sc8);
      *(short8*)&Bs[row][sc8] = load8_bf(Bw + (Bbase + row) * 256 + k0 + sc8);
    }
    __syncthreads();
    short8 af[4], bfr[4];
    for (int ms = 0; ms < 4; ms++) af[ms]  = *(const short8*)&As[wm + ms*16 + l15][quad*8];
    for (int ns = 0; ns < 4; ns++) bfr[ns] = *(const short8*)&Bs[wn + ns*16 + l15][quad*8];
    for (int ms = 0; ms < 4; ms++)
      for (int ns = 0; ns < 4; ns++)
        acc[ms][ns] = __builtin_amdgcn_mfma_f32_16x16x32_bf16(af[ms], bfr[ns], acc[ms][ns], 0, 0, 0);
  }

  for (int ms = 0; ms < 4; ms++) {
    int rowl = wm + ms*16 + quad*4;
    for (int ns = 0; ns < 4; ns++) {
      int col = (int)Bbase + wn + ns*16 + l15;
      int bidx = col >> 11, scol = col & 2047;
      for (int r = 0; r < 4; r++) {
        long m = Abase + rowl + r;
        Ut[((long)bidx * 2048 + m) * 2048 + scol] = f2bf(acc[ms][ns][r] + cbias[m]);
      }
    }
  }
}

// Fused attention (r3/r9 structure) -> fp16 per-head partials.
__device__ inline void attn_body(const short* __restrict__ Kp,
                                 const short* __restrict__ Qp,
                                 const short* __restrict__ Ut,
                                 _Float16* __restrict__ partial,
                                 int L, char* smem) {
  typedef short PtRow[136];
  PtRow* Pt   = (PtRow*)smem;                     // [2*128][136]
  float* psum = (float*)(smem + 2*128*136*2);     // [128][4] flat

  const int tid  = threadIdx.x;
  const int wave = tid >> 6, lane = tid & 63;
  const int l15  = lane & 15, quad = lane >> 4;

  const int h  = L & 7;
  const int b  = (L >> 3) & 3;
  const int q0 = (L >> 5) * 128;

  const short* Kbh = Kp + (long)b * T * DM + h * DK;
  const short* Qbh = Qp + (long)b * T * DM + h * DK;
  const short* Ubh = Ut + ((long)b * 2048 + h * 256) * 2048;

  float4v acc[4][8];
  for (int i = 0; i < 4; i++)
    for (int j = 0; j < 8; j++)
      for (int r = 0; r < 4; r++) acc[i][j][r] = 0.f;

  float ps[8];
  for (int i = 0; i < 8; i++) ps[i] = 0.f;

  short8 qf[8];
  for (int qs = 0; qs < 8; qs++)
    qf[qs] = *(const short8*)(Qbh + (long)(q0 + qs*16 + l15) * DM + quad*8);

  auto computeSt = [&](int s0, int buf) {
    for (int ss = 0; ss < 2; ss++) {
      short8 kf = *(const short8*)(Kbh + (long)(s0 + wave*32 + ss*16 + l15) * DM + quad*8);
      for (int qs = 0; qs < 8; qs++) {
        float4v z = {0.f, 0.f, 0.f, 0.f};
        float4v st = __builtin_amdgcn_mfma_f32_16x16x32_bf16(kf, qf[qs], z, 0, 0, 0);
        float p0 = fexp2(st[0]), p1 = fexp2(st[1]);
        float p2 = fexp2(st[2]), p3 = fexp2(st[3]);
        ps[qs] += (p0 + p1) + (p2 + p3);
        uint2v pb; pb[0] = pk2(p0, p1); pb[1] = pk2(p2, p3);
        *(uint2v*)&Pt[buf*128 + qs*16 + l15][wave*32 + ss*16 + quad*4] = pb;
      }
    }
  };

  computeSt(0, 0);

  for (int it = 0; it < T / 128; it++) {
    const int buf = it & 1;
    const int s0  = it * 128;
    __syncthreads();
    if (it < T / 128 - 1) computeSt(s0 + 128, buf ^ 1);
    for (int ks = 0; ks < 4; ks++) {
      short8 pf[8];
      for (int ns = 0; ns < 8; ns++)
        pf[ns] = *(const short8*)&Pt[buf*128 + ns*16 + l15][ks*32 + quad*8];
      for (int ms = 0; ms < 4; ms++) {
        short8 vf = *(const short8*)(Ubh + (long)(wave*64 + ms*16 + l15) * 2048
                                     + s0 + ks*32 + quad*8);
        for (int ns = 0; ns < 8; ns++)
          acc[ms][ns] = __builtin_amdgcn_mfma_f32_16x16x32_bf16(vf, pf[ns], acc[ms][ns], 0, 0, 0);
      }
    }
  }

  for (int qs = 0; qs < 8; qs++) {
    ps[qs] += __shfl_xor(ps[qs], 16, 64);
    ps[qs] += __shfl_xor(ps[qs], 32, 64);
  }
  if (lane < 16)
    for (int qs = 0; qs < 8; qs++) psum[(qs*16 + lane)*4 + wave] = ps[qs];
  __syncthreads();

  for (int ns = 0; ns < 8; ns++) {
    float4v sv = *(const float4v*)&psum[(ns*16 + l15)*4];
    float rl = 1.0f / (sv[0] + sv[1] + sv[2] + sv[3]);
    long pbase = ((long)h * 8192 + b * T + q0 + ns*16 + l15) * 256;
    for (int ms = 0; ms < 4; ms++) {
      int ncol = wave*64 + ms*16 + quad*4;
      half4 hv;
      for (int r = 0; r < 4; r++) hv[r] = (_Float16)(acc[ms][ns][r] * rl);
      *(half4*)(partial + pbase + ncol) = hv;
    }
  }
}

// ============================ mega (cooperative) ===========================
__global__ __launch_bounds__(256, 2)
void mega(const float* __restrict__ key_x, const float* __restrict__ query_x,
          const float* __restrict__ value_x,
          const float* __restrict__ WK_w, const float* __restrict__ WK_b,
          const float* __restrict__ WQ_w, const float* __restrict__ WQ_b,
          const float* __restrict__ WV_w, const float* __restrict__ WV_b,
          const float* __restrict__ WO_w, const float* __restrict__ WO_b,
          short* __restrict__ Kp, short* __restrict__ Qp,
          short* __restrict__ Ut, short* __restrict__ Wf,
          float* __restrict__ cbias, _Float16* __restrict__ part,
          float* __restrict__ outp) {
  __shared__ __align__(16) char smem[71680];
  cg::grid_group grid = cg::this_grid();
  const int gb = blockIdx.x;

  // phase 0: projections + Wfused + cbias
  if (gb < 256)
    proj_body(key_x, WK_w, WK_b, Kp, 1.0f, gb & 63, gb >> 6, smem);
  else
    proj_body(query_x, WQ_w, WQ_b, Qp, 1.44269504f, (gb - 256) & 63, (gb - 256) >> 6, smem);
  __syncthreads();
  if (gb < 64)
    wf_body(WO_w, WV_w, Wf, gb >> 3, (gb >> 2) & 1, gb & 3, smem);
  else if (gb < 192)
    cbias_body(WV_b, WO_w, cbias, gb - 64, smem);

  __threadfence();
  grid.sync();

  // phase 1: Ut (1024 jobs, 2 per block)
  for (int jj = gb; jj < 1024; jj += 512)
    ut_body(Wf, value_x, cbias, Ut, jj & 15, jj >> 4, smem);

  __threadfence();
  grid.sync();

  // phase 2: attention
  attn_body(Kp, Qp, Ut, part, gb, smem);

  __threadfence();
  grid.sync();

  // phase 3: reduce partials + bias -> out
  {
    const long HP = 8192L * 256;
    for (int it = 0; it < 4; it++) {
      long i4 = ((long)gb * 1024 + it * 256 + threadIdx.x) * 4;
      float4v o = *(const float4v*)(WO_b + (i4 & 255));
      for (int h = 0; h < 8; h++) {
        half4 hv = *(const half4*)(part + h * HP + i4);
        for (int r = 0; r < 4; r++) o[r] += (float)hv[r];
      }
      *(float4v*)(outp + i4) = o;
    }
  }
}

// ========================= fallback (r9 pipeline) ==========================
__global__ __launch_bounds__(256)
void prep_k(const float* key_x, const float* query_x,
            const float* WK_w, const float* WK_b,
            const float* WQ_w, const float* WQ_b,
            const float* WV_w, const float* WV_b, const float* WO_w,
            short* Kp, short* Qp, short* Wf, float* cbias) {
  __shared__ __align__(16) char smem[15360];
  const int gb = blockIdx.x;
  if (gb < 256)
    proj_body(key_x, WK_w, WK_b, Kp, 1.0f, gb & 63, gb >> 6, smem);
  else if (gb < 512)
    proj_body(query_x, WQ_w, WQ_b, Qp, 1.44269504f, (gb - 256) & 63, (gb - 256) >> 6, smem);
  else if (gb < 576) {
    int w = gb - 512;
    wf_body(WO_w, WV_w, Wf, w >> 3, (w >> 2) & 1, w & 3, smem);
  } else
    cbias_body(WV_b, WO_w, cbias, gb - 576, smem);
}

__global__ __launch_bounds__(256)
void ut_k(const short* Wf, const float* Bw, const float* cbias, short* Ut) {
  __shared__ __align__(16) char smem[20480];
  ut_body(Wf, Bw, cbias, Ut, blockIdx.x, blockIdx.y, smem);
}

__global__ __launch_bounds__(256, 2)
void attn_k(const short* Kp, const short* Qp, const short* Ut, _Float16* part) {
  __shared__ __align__(16) char smem[71680];
  attn_body(Kp, Qp, Ut, part, blockIdx.x, smem);
}

__global__ void reduce_k(const _Float16* __restrict__ partial,
                         const float* __restrict__ WO_b,
                         float* __restrict__ out) {
  const long HP = 8192L * 256;
  long i4 = ((long)blockIdx.x * 256 + threadIdx.x) * 4;
  float4v o = *(const float4v*)(WO_b + (i4 & 255));
  for (int h = 0; h < 8; h++) {
    half4 hv = *(const half4*)(partial + h * HP + i4);
    for (int r = 0; r < 4; r++) o[r] += (float)hv[r];
  }
  *(float4v*)(out + i4) = o;
}

// ---------------------------------------------------------------------------
extern "C" void kernel_launch(void* const* d_in, const int* in_sizes, int n_in,
                              void* d_out, int out_size, void* d_ws, size_t ws_size,
                              hipStream_t stream) {
  const float* key_x   = (const float*)d_in[0];
  const float* query_x = (const float*)d_in[1];
  const float* value_x = (const float*)d_in[2];
  const float* WK_w = (const float*)d_in[4];
  const float* WK_b = (const float*)d_in[5];
  const float* WQ_w = (const float*)d_in[6];
  const float* WQ_b = (const float*)d_in[7];
  const float* WV_w = (const float*)d_in[8];
  const float* WV_b = (const float*)d_in[9];
  const float* WO_w = (const float*)d_in[10];
  const float* WO_b = (const float*)d_in[11];

  char* ws = (char*)d_ws;
  short*     Kp    = (short*)(ws);                  //  4 MB  [8192][256] bf16
  short*     Qp    = (short*)(ws + (4u  << 20));    //  4 MB  (x log2e)
  short*     Ut    = (short*)(ws + (8u  << 20));    // 32 MB  [4][2048][2048] bf16
  short*     Wf    = (short*)(ws + (40u << 20));    //  1 MB  [8*256][256] bf16
  float*     cbias = (float*)(ws + (41u << 20));    //  8 KB  [8][256] fp32
  _Float16*  part  = (_Float16*)(ws + (42u << 20)); // 32 MB  [8][8192][256] fp16
  float*     outp  = (float*)d_out;

  int nb = 0;
  hipError_t qe = hipOccupancyMaxActiveBlocksPerMultiprocessor(&nb, mega, 256, 0);
  bool done = false;
  if (qe == hipSuccess && nb >= 2) {
    void* args[] = {
      (void*)&key_x, (void*)&query_x, (void*)&value_x,
      (void*)&WK_w, (void*)&WK_b, (void*)&WQ_w, (void*)&WQ_b,
      (void*)&WV_w, (void*)&WV_b, (void*)&WO_w, (void*)&WO_b,
      (void*)&Kp, (void*)&Qp, (void*)&Ut, (void*)&Wf,
      (void*)&cbias, (void*)&part, (void*)&outp
    };
    hipError_t e = hipLaunchCooperativeKernel((const void*)mega, dim3(512),
                                              dim3(256), args, 0, stream);
    done = (e == hipSuccess);
  }
  if (!done) {
    prep_k<<<704, 256, 0, stream>>>(key_x, query_x, WK_w, WK_b, WQ_w, WQ_b,
                                    WV_w, WV_b, WO_w, Kp, Qp, Wf, cbias);
    ut_k<<<dim3(16, 64), 256, 0, stream>>>(Wf, value_x, cbias, Ut);
    attn_k<<<512, 256, 0, stream>>>(Kp, Qp, Ut, part);
    reduce_k<<<2048, 256, 0, stream>>>(part, WO_b, outp);
  }
}

// Round 11
// 304.099 us; speedup vs baseline: 1.3240x; 1.3240x over previous
//
#include <hip/hip_runtime.h>

typedef __attribute__((ext_vector_type(8))) short short8;
typedef __attribute__((ext_vector_type(4))) short short4v;
typedef __attribute__((ext_vector_type(4))) float float4v;
typedef __attribute__((ext_vector_type(4))) unsigned uint4v;
typedef __attribute__((ext_vector_type(2))) unsigned uint2v;
typedef __attribute__((ext_vector_type(4))) _Float16 half4;

constexpr int T  = 2048;
constexpr int DM = 256;
constexpr int DK = 32;

__device__ inline short f2bf(float f) {
  unsigned u = __builtin_bit_cast(unsigned, f);
  u += 0x7fff + ((u >> 16) & 1);            // RNE
  return (short)(u >> 16);
}

__device__ inline unsigned pk2(float a, float b) {
#if __has_builtin(__builtin_amdgcn_cvt_pk_bf16_f32)
  auto r = __builtin_amdgcn_cvt_pk_bf16_f32(a, b);
  return __builtin_bit_cast(unsigned, r);
#else
  unsigned ua = __builtin_bit_cast(unsigned, a);
  ua = (ua + 0x7fff + ((ua >> 16) & 1)) >> 16;
  unsigned ub = __builtin_bit_cast(unsigned, b);
  ub = (ub + 0x7fff + ((ub >> 16) & 1)) >> 16;
  return ua | (ub << 16);
#endif
}

__device__ inline float fexp2(float x) {
#if __has_builtin(__builtin_amdgcn_exp2f)
  return __builtin_amdgcn_exp2f(x);
#else
  return exp2f(x);
#endif
}

__device__ inline short8 load8_bf(const float* __restrict__ p) {
  float4v a = *(const float4v*)p;
  float4v b = *(const float4v*)(p + 4);
  uint4v u;
  u[0] = pk2(a[0], a[1]); u[1] = pk2(a[2], a[3]);
  u[2] = pk2(b[0], b[1]); u[3] = pk2(b[2], b[3]);
  return __builtin_bit_cast(short8, u);
}

// ===== phase bodies — LDS passed as TYPED ARRAY REFERENCES only.
// (r10 pitfall: passing LDS as char* loses the address space -> flat
//  addressing -> ~400 MB scratch spill traffic. Never again.)

// K/Q projection: 128x64 tile, fp32 in -> bf16 out, K=N=256.
__device__ inline void proj_body(const float* __restrict__ A,
                                 const float* __restrict__ Bw,
                                 const float* __restrict__ bias,
                                 short* __restrict__ C, float oscale,
                                 int bx, int by,
                                 short (&As)[128][40], short (&Bs)[128][40]) {
  const int tid  = threadIdx.x;
  const int wave = tid >> 6, lane = tid & 63;
  const int l15  = lane & 15, quad = lane >> 4;
  const int wm   = (wave & 1) * 64, wn = (wave >> 1) * 32;
  const long Abase = (long)bx * 128;
  const long Bbase = (long)by * 64;

  float4v acc[4][2];
  for (int i = 0; i < 4; i++)
    for (int j = 0; j < 2; j++)
      for (int r = 0; r < 4; r++) acc[i][j][r] = 0.f;

  const int srow = tid >> 2;
  const int sc8  = (tid & 3) * 8;

  for (int k0 = 0; k0 < 256; k0 += 32) {
    __syncthreads();
    for (int i = 0; i < 2; i++) {
      int row = srow + i * 64;
      *(short8*)&As[row][sc8] = load8_bf(A + (Abase + row) * 256 + k0 + sc8);
    }
    *(short8*)&Bs[srow][sc8] = load8_bf(Bw + (Bbase + srow) * 256 + k0 + sc8);
    __syncthreads();
    short8 af[4], bfr[2];
    for (int ms = 0; ms < 4; ms++) af[ms]  = *(const short8*)&As[wm + ms*16 + l15][quad*8];
    for (int ns = 0; ns < 2; ns++) bfr[ns] = *(const short8*)&Bs[wn + ns*16 + l15][quad*8];
    for (int ms = 0; ms < 4; ms++)
      for (int ns = 0; ns < 2; ns++)
        acc[ms][ns] = __builtin_amdgcn_mfma_f32_16x16x32_bf16(af[ms], bfr[ns], acc[ms][ns], 0, 0, 0);
  }

  for (int ms = 0; ms < 4; ms++) {
    int rowl = wm + ms*16 + quad*4;
    for (int ns = 0; ns < 2; ns++) {
      int col = (int)Bbase + wn + ns*16 + l15;
      float bv = bias[col];
      for (int r = 0; r < 4; r++) {
        long row = Abase + rowl + r;
        C[row * 256 + col] = f2bf((acc[ms][ns][r] + bv) * oscale);
      }
    }
  }
}

// Wfused[h][n][k] = sum_d WO_w[n, d*8+h] * WV_w[h*256+d, k], bf16 out.
__device__ inline void wf_body(const float* __restrict__ WO_w,
                               const float* __restrict__ WV_w,
                               short* __restrict__ Wf,
                               int h, int bx, int by,
                               short (&As)[128][40], short (&Bs)[128][40]) {
  const int tid  = threadIdx.x;
  const int wave = tid >> 6, lane = tid & 63;
  const int l15  = lane & 15, quad = lane >> 4;
  const int wm   = (wave & 1) * 64, wn = (wave >> 1) * 32;
  const int srow = tid >> 2, sc8 = (tid & 3) * 8;

  float4v acc[4][2];
  for (int i = 0; i < 4; i++)
    for (int j = 0; j < 2; j++)
      for (int r = 0; r < 4; r++) acc[i][j][r] = 0.f;

  for (int d0 = 0; d0 < 256; d0 += 32) {
    __syncthreads();
    for (int i = 0; i < 2; i++) {
      int row = srow + i * 64;
      for (int j = 0; j < 8; j++)
        As[row][sc8 + j] = f2bf(WO_w[(bx*128 + row) * 2048 + (d0 + sc8 + j) * 8 + h]);
    }
    for (int j = 0; j < 8; j++)
      Bs[srow][sc8 + j] = f2bf(WV_w[((h*256) + d0 + sc8 + j) * 256 + by*64 + srow]);
    __syncthreads();
    short8 af[4], bfr[2];
    for (int ms = 0; ms < 4; ms++) af[ms]  = *(const short8*)&As[wm + ms*16 + l15][quad*8];
    for (int ns = 0; ns < 2; ns++) bfr[ns] = *(const short8*)&Bs[wn + ns*16 + l15][quad*8];
    for (int ms = 0; ms < 4; ms++)
      for (int ns = 0; ns < 2; ns++)
        acc[ms][ns] = __builtin_amdgcn_mfma_f32_16x16x32_bf16(af[ms], bfr[ns], acc[ms][ns], 0, 0, 0);
  }
  for (int ms = 0; ms < 4; ms++) {
    int m = bx*128 + wm + ms*16 + quad*4;
    for (int ns = 0; ns < 2; ns++) {
      int col = by*64 + wn + ns*16 + l15;
      for (int r = 0; r < 4; r++)
        Wf[((long)h*256 + m + r) * 256 + col] = f2bf(acc[ms][ns][r]);
    }
  }
}

// Ut[b][h*256+n][s] = sum_k Wf[h*256+n][k]*value_x[b*2048+s][k] + cbias[.]
__device__ inline void ut_body(const short* __restrict__ Wf,
                               const float* __restrict__ Bw,
                               const float* __restrict__ cbias,
                               short* __restrict__ Ut,
                               int bx, int by,
                               short (&As)[128][40], short (&Bs)[128][40]) {
  const int tid  = threadIdx.x;
  const int wave = tid >> 6, lane = tid & 63;
  const int l15  = lane & 15, quad = lane >> 4;
  const int wm   = (wave & 1) * 64, wn = (wave >> 1) * 64;
  const long Abase = (long)bx * 128;
  const long Bbase = (long)by * 128;

  float4v acc[4][4];
  for (int i = 0; i < 4; i++)
    for (int j = 0; j < 4; j++)
      for (int r = 0; r < 4; r++) acc[i][j][r] = 0.f;

  const int srow = tid >> 2;
  const int sc8  = (tid & 3) * 8;

  for (int k0 = 0; k0 < 256; k0 += 32) {
    __syncthreads();
    for (int i = 0; i < 2; i++) {
      int row = srow + i * 64;
      *(short8*)&As[row][sc8] = *(const short8*)(Wf + (Abase + row) * 256 + k0 + sc8);
      *(short8*)&Bs[row][sc8] = load8_bf(Bw + (Bbase + row) * 256 + k0 + sc8);
    }
    __syncthreads();
    short8 af[4], bfr[4];
    for (int ms = 0; ms < 4; ms++) af[ms]  = *(const short8*)&As[wm + ms*16 + l15][quad*8];
    for (int ns = 0; ns < 4; ns++) bfr[ns] = *(const short8*)&Bs[wn + ns*16 + l15][quad*8];
    for (int ms = 0; ms < 4; ms++)
      for (int ns = 0; ns < 4; ns++)
        acc[ms][ns] = __builtin_amdgcn_mfma_f32_16x16x32_bf16(af[ms], bfr[ns], acc[ms][ns], 0, 0, 0);
  }

  for (int ms = 0; ms < 4; ms++) {
    int rowl = wm + ms*16 + quad*4;
    for (int ns = 0; ns < 4; ns++) {
      int col = (int)Bbase + wn + ns*16 + l15;
      int bidx = col >> 11, scol = col & 2047;
      for (int r = 0; r < 4; r++) {
        long m = Abase + rowl + r;
        Ut[((long)bidx * 2048 + m) * 2048 + scol] = f2bf(acc[ms][ns][r] + cbias[m]);
      }
    }
  }
}

// ---------------------------------------------------------------------------
// prep1 (192 blocks): Wf (64) + cbias (128) — the only ut dependencies.
// ---------------------------------------------------------------------------
__global__ __launch_bounds__(256)
void prep1(const float* __restrict__ WV_w, const float* __restrict__ WV_b,
           const float* __restrict__ WO_w,
           short* __restrict__ Wf, float* __restrict__ cbias) {
  __shared__ __align__(16) short As[128][40];
  __shared__ __align__(16) short Bs[128][40];
  __shared__ float cb_s[16][17];
  const int gb  = blockIdx.x;
  const int tid = threadIdx.x;

  if (gb < 64) {
    wf_body(WO_w, WV_w, Wf, gb >> 3, (gb >> 2) & 1, gb & 3, As, Bs);
  } else {
    const int idx = gb - 64;
    const int h = idx >> 4, ng = idx & 15;
    const int ni = tid & 15, di = tid >> 4;
    const int n = ng * 16 + ni;
    float acc = 0.f;
    for (int j = 0; j < 16; j++) {
      int d = di * 16 + j;
      acc += WV_b[h*256 + d] * WO_w[n * 2048 + d*8 + h];
    }
    cb_s[ni][di] = acc;
    __syncthreads();
    if (tid < 16) {
      float s = 0.f;
      for (int d2 = 0; d2 < 16; d2++) s += cb_s[tid][d2];
      cbias[h*256 + ng*16 + tid] = s;
    }
  }
}

// ---------------------------------------------------------------------------
// front (1536 blocks): co-schedules Ut GEMM (1024) with the independent
// K projection (256) and Q projection (256) — fills 6 blocks/CU of
// heterogeneous work instead of two under-filled sequential launches.
// ---------------------------------------------------------------------------
__global__ __launch_bounds__(256)
void front(const float* __restrict__ key_x, const float* __restrict__ query_x,
           const float* __restrict__ value_x,
           const float* __restrict__ WK_w, const float* __restrict__ WK_b,
           const float* __restrict__ WQ_w, const float* __restrict__ WQ_b,
           const short* __restrict__ Wf, const float* __restrict__ cbias,
           short* __restrict__ Kp, short* __restrict__ Qp,
           short* __restrict__ Ut) {
  __shared__ __align__(16) short As[128][40];
  __shared__ __align__(16) short Bs[128][40];
  const int gb = blockIdx.x;

  if (gb < 1024) {
    ut_body(Wf, value_x, cbias, Ut, gb & 15, gb >> 4, As, Bs);
  } else if (gb < 1280) {
    const int g = gb - 1024;
    proj_body(key_x, WK_w, WK_b, Kp, 1.0f, g & 63, g >> 6, As, Bs);
  } else {
    const int g = gb - 1280;
    proj_body(query_x, WQ_w, WQ_b, Qp, 1.44269504f, g & 63, g >> 6, As, Bs);
  }
}

// ---------------------------------------------------------------------------
// Fused attention — r9 VERBATIM (measured 122.8 us). q-tile 128, no online
// max (|S| <= ~11 -> exact), Qp pre-scaled by log2(e), double-buffered Pt,
// ONE barrier per s-iter. Grid 512; h = id%8 (XCD head locality for Ut).
// Epilogue: normalize, store fp16 per-head partial (plain stores).
// ---------------------------------------------------------------------------
__global__ __launch_bounds__(256, 2)
void attn_kernel(const short* __restrict__ Kp, const short* __restrict__ Qp,
                 const short* __restrict__ Ut, _Float16* __restrict__ partial) {
  __shared__ __align__(16) short Pt[2][128][136];
  __shared__ __align__(16) float psum[128][4];

  const int tid  = threadIdx.x;
  const int wave = tid >> 6, lane = tid & 63;
  const int l15  = lane & 15, quad = lane >> 4;

  const int L  = blockIdx.x;
  const int h  = L & 7;
  const int b  = (L >> 3) & 3;
  const int q0 = (L >> 5) * 128;

  const short* Kbh = Kp + (long)b * T * DM + h * DK;
  const short* Qbh = Qp + (long)b * T * DM + h * DK;
  const short* Ubh = Ut + ((long)b * 2048 + h * 256) * 2048;

  float4v acc[4][8];
  for (int i = 0; i < 4; i++)
    for (int j = 0; j < 8; j++)
      for (int r = 0; r < 4; r++) acc[i][j][r] = 0.f;

  float ps[8];
  for (int i = 0; i < 8; i++) ps[i] = 0.f;

  short8 qf[8];
  for (int qs = 0; qs < 8; qs++)
    qf[qs] = *(const short8*)(Qbh + (long)(q0 + qs*16 + l15) * DM + quad*8);

  auto computeSt = [&](int s0, int buf) {
    for (int ss = 0; ss < 2; ss++) {
      short8 kf = *(const short8*)(Kbh + (long)(s0 + wave*32 + ss*16 + l15) * DM + quad*8);
      for (int qs = 0; qs < 8; qs++) {
        float4v z = {0.f, 0.f, 0.f, 0.f};
        float4v st = __builtin_amdgcn_mfma_f32_16x16x32_bf16(kf, qf[qs], z, 0, 0, 0);
        float p0 = fexp2(st[0]), p1 = fexp2(st[1]);
        float p2 = fexp2(st[2]), p3 = fexp2(st[3]);
        ps[qs] += (p0 + p1) + (p2 + p3);
        uint2v pb; pb[0] = pk2(p0, p1); pb[1] = pk2(p2, p3);
        *(uint2v*)&Pt[buf][qs*16 + l15][wave*32 + ss*16 + quad*4] = pb;
      }
    }
  };

  computeSt(0, 0);

  for (int it = 0; it < T / 128; it++) {
    const int buf = it & 1;
    const int s0  = it * 128;
    __syncthreads();
    if (it < T / 128 - 1) computeSt(s0 + 128, buf ^ 1);
    for (int ks = 0; ks < 4; ks++) {
      short8 pf[8];
      for (int ns = 0; ns < 8; ns++)
        pf[ns] = *(const short8*)&Pt[buf][ns*16 + l15][ks*32 + quad*8];
      for (int ms = 0; ms < 4; ms++) {
        short8 vf = *(const short8*)(Ubh + (long)(wave*64 + ms*16 + l15) * 2048
                                     + s0 + ks*32 + quad*8);
        for (int ns = 0; ns < 8; ns++)
          acc[ms][ns] = __builtin_amdgcn_mfma_f32_16x16x32_bf16(vf, pf[ns], acc[ms][ns], 0, 0, 0);
      }
    }
  }

  for (int qs = 0; qs < 8; qs++) {
    ps[qs] += __shfl_xor(ps[qs], 16, 64);
    ps[qs] += __shfl_xor(ps[qs], 32, 64);
  }
  if (lane < 16)
    for (int qs = 0; qs < 8; qs++) psum[qs*16 + lane][wave] = ps[qs];
  __syncthreads();

  for (int ns = 0; ns < 8; ns++) {
    float4v sv = *(const float4v*)&psum[ns*16 + l15][0];
    float rl = 1.0f / (sv[0] + sv[1] + sv[2] + sv[3]);
    long pbase = ((long)h * 8192 + b * T + q0 + ns*16 + l15) * 256;
    for (int ms = 0; ms < 4; ms++) {
      int ncol = wave*64 + ms*16 + quad*4;
      half4 hv;
      for (int r = 0; r < 4; r++) hv[r] = (_Float16)(acc[ms][ns][r] * rl);
      *(half4*)(partial + pbase + ncol) = hv;
    }
  }
}

// ---------------------------------------------------------------------------
// out[row][n] = WO_b[n] + sum_h partial[h][row][n]
// ---------------------------------------------------------------------------
__global__ void reduce_out(const _Float16* __restrict__ partial,
                           const float* __restrict__ WO_b,
                           float* __restrict__ out) {
  const long HP = 8192L * 256;
  long i4 = ((long)blockIdx.x * 256 + threadIdx.x) * 4;
  float4v o = *(const float4v*)(WO_b + (i4 & 255));
  for (int h = 0; h < 8; h++) {
    half4 hv = *(const half4*)(partial + h * HP + i4);
    for (int r = 0; r < 4; r++) o[r] += (float)hv[r];
  }
  *(float4v*)(out + i4) = o;
}

// ---------------------------------------------------------------------------
extern "C" void kernel_launch(void* const* d_in, const int* in_sizes, int n_in,
                              void* d_out, int out_size, void* d_ws, size_t ws_size,
                              hipStream_t stream) {
  const float* key_x   = (const float*)d_in[0];
  const float* query_x = (const float*)d_in[1];
  const float* value_x = (const float*)d_in[2];
  const float* WK_w = (const float*)d_in[4];
  const float* WK_b = (const float*)d_in[5];
  const float* WQ_w = (const float*)d_in[6];
  const float* WQ_b = (const float*)d_in[7];
  const float* WV_w = (const float*)d_in[8];
  const float* WV_b = (const float*)d_in[9];
  const float* WO_w = (const float*)d_in[10];
  const float* WO_b = (const float*)d_in[11];

  char* ws = (char*)d_ws;
  short*     Kp    = (short*)(ws);                  //  4 MB  [8192][256] bf16
  short*     Qp    = (short*)(ws + (4u  << 20));    //  4 MB  (x log2e)
  short*     Ut    = (short*)(ws + (8u  << 20));    // 32 MB  [4][2048][2048] bf16
  short*     Wf    = (short*)(ws + (40u << 20));    //  1 MB  [8*256][256] bf16
  float*     cbias = (float*)(ws + (41u << 20));    //  8 KB  [8][256] fp32
  _Float16*  part  = (_Float16*)(ws + (42u << 20)); // 32 MB  [8][8192][256] fp16
  float*     outp  = (float*)d_out;

  prep1<<<192, 256, 0, stream>>>(WV_w, WV_b, WO_w, Wf, cbias);
  front<<<1536, 256, 0, stream>>>(key_x, query_x, value_x,
                                  WK_w, WK_b, WQ_w, WQ_b,
                                  Wf, cbias, Kp, Qp, Ut);
  attn_kernel<<<512, 256, 0, stream>>>(Kp, Qp, Ut, part);
  reduce_out<<<2048, 256, 0, stream>>>(part, WO_b, outp);
}